// Round 8
// baseline (296.250 us; speedup 1.0000x reference)
//
#include <hip/hip_runtime.h>
#include <hip/hip_bf16.h>

typedef __bf16 bf16;
typedef __attribute__((ext_vector_type(8))) __bf16 bf16x8;
typedef __attribute__((ext_vector_type(4))) __bf16 bf16x4;
typedef __attribute__((ext_vector_type(4))) float f32x4;

// ---------------------------------------------------------------- constants
#define B_SZ 2
#define S_SZ 2048
#define D_SZ 2048
#define H_SZ 32
#define KV_SZ 8
#define HD_SZ 64
#define M_SZ (B_SZ * S_SZ)   // 4096
#define NQKV 3072            // 2048 Q + 512 K + 512 V packed weight rows

// async global->LDS, 16B per lane; LDS dest = wave-uniform base + lane*16
#define GLDS(g, s) __builtin_amdgcn_global_load_lds( \
    (const __attribute__((address_space(1))) void*)(g), \
    (__attribute__((address_space(3))) void*)(s), 16, 0, 0)

// ---------------------------------------------------------------- fused conversions
// single dispatch: x -> xb, [Wq;Wk;Wv] -> Wf, Wo -> wob (all bf16)
__global__ void cvt_all(const float* __restrict__ x, const float* __restrict__ Wq,
                        const float* __restrict__ Wk, const float* __restrict__ Wv,
                        const float* __restrict__ Wo,
                        bf16* __restrict__ xb, bf16* __restrict__ Wf, bf16* __restrict__ wob,
                        int nx, int n1, int n2) {
    int i = blockIdx.x * blockDim.x + threadIdx.x;
    const float* src; bf16* dst; int off;
    if (i < nx)                 { src = x;  dst = xb; off = i; }
    else {
        int j = i - nx;
        if (j < n1)             { src = Wq; dst = Wf; off = j; }
        else if (j < n1 + n2)   { src = Wk; dst = Wf + (size_t)4 * n1; off = j - n1; }
        else if (j < n1 + 2*n2) { src = Wv; dst = Wf + (size_t)4 * (n1 + n2); off = j - n1 - n2; }
        else if (j < 2*n1+2*n2) { src = Wo; dst = wob; off = j - n1 - 2 * n2; }
        else return;
    }
    float4 v = ((const float4*)src)[off];
    bf16x4 o;
    o.x = (bf16)v.x; o.y = (bf16)v.y; o.z = (bf16)v.z; o.w = (bf16)v.w;
    ((bf16x4*)dst)[off] = o;
}

// ---------------------------------------------------------------- GEMM core v2
// 128-thread block (2 waves). Wave w computes rows [w*64, w*64+64) x all 128 cols
// (acc 4x8). XOR-swizzled contiguous LDS tiles [128][64] (glds-compatible):
// 16B chunk q of row r lives at position q ^ (r&7). Staging lane l fetches
// global chunk (l&7)^(l>>3) -> swizzle is free, frag b128 reads conflict-free.
#define GEMM_CORE2(A_, B_, Kdim)                                                 \
    const int tid  = threadIdx.x;                                                \
    const int w    = tid >> 6;                                                   \
    const int lane = tid & 63;                                                   \
    const int c = lane & 15, quad = lane >> 4;                                   \
    const int g8 = lane >> 3;                                                    \
    const int chs = ((lane & 7) ^ g8) * 8;                                       \
    const int rowBase = blockIdx.y * 128;                                        \
    const int colBase = blockIdx.x * 128;                                        \
    const bf16* Ag = A_ + (size_t)(rowBase + w * 64 + g8) * Kdim + chs;          \
    const bf16* Bg = B_ + (size_t)(colBase + w * 64 + g8) * Kdim + chs;          \
    bf16* sAw = As + (w * 64) * 64;                                              \
    bf16* sBw = Bs + (w * 64) * 64;                                              \
    f32x4 acc[4][8] = {};                                                        \
    for (int k0 = 0; k0 < Kdim; k0 += 64) {                                      \
        _Pragma("unroll")                                                        \
        for (int j = 0; j < 8; j++) {                                            \
            GLDS(Ag + (size_t)(j * 8) * Kdim + k0, sAw + j * 512);               \
            GLDS(Bg + (size_t)(j * 8) * Kdim + k0, sBw + j * 512);               \
        }                                                                        \
        __syncthreads();                                                         \
        _Pragma("unroll")                                                        \
        for (int ks = 0; ks < 2; ks++) {                                         \
            bf16x8 af[4], bfr[8];                                                \
            _Pragma("unroll")                                                    \
            for (int mi = 0; mi < 4; mi++)                                       \
                af[mi] = *(const bf16x8*)(As + (w * 64 + mi * 16 + c) * 64       \
                                          + (((ks << 2) + quad) ^ (c & 7)) * 8); \
            _Pragma("unroll")                                                    \
            for (int ni = 0; ni < 8; ni++)                                       \
                bfr[ni] = *(const bf16x8*)(Bs + (ni * 16 + c) * 64               \
                                          + (((ks << 2) + quad) ^ (c & 7)) * 8); \
            _Pragma("unroll")                                                    \
            for (int mi = 0; mi < 4; mi++)                                       \
                _Pragma("unroll")                                                \
                for (int ni = 0; ni < 8; ni++)                                   \
                    acc[mi][ni] = __builtin_amdgcn_mfma_f32_16x16x32_bf16(       \
                        af[mi], bfr[ni], acc[mi][ni], 0, 0, 0);                  \
        }                                                                        \
        __syncthreads();                                                         \
    }                                                                            \
    const int mBase = rowBase + w * 64;

// ---------------------------------------------------------------- fused QKV GEMM
__global__ __launch_bounds__(128, 2)
void gemm_qkv(const bf16* __restrict__ A, const bf16* __restrict__ Bw,
              bf16* __restrict__ Qb, bf16* __restrict__ Kb, bf16* __restrict__ Vtb,
              const float* __restrict__ cosp, const float* __restrict__ sinp,
              float qscale)
{
    __shared__ __align__(16) bf16 As[128 * 64];
    __shared__ __align__(16) bf16 Bs[128 * 64];

    GEMM_CORE2(A, Bw, D_SZ)

    // wave's 128 cols = two 64-wide heads; Q/K/V boundaries are 128-aligned
#pragma unroll
    for (int half = 0; half < 2; half++) {
        const int hcol = colBase + half * 64;
        const int no   = half * 4;
        if (hcol < 2560) {
            // ---- RoPE path (Q or K)
            bf16* dst; int hh, Hn; float sc;
            if (hcol < 2048) { dst = Qb; hh = hcol >> 6;        Hn = H_SZ;  sc = qscale; }
            else             { dst = Kb; hh = (hcol >> 6) - 32; Hn = KV_SZ; sc = 1.0f;  }
#pragma unroll
            for (int mi = 0; mi < 4; mi++) {
#pragma unroll
                for (int r = 0; r < 4; r++) {
                    int row = mBase + mi * 16 + quad * 4 + r;
                    int b = row >> 11;           // S = 2048
                    int s = row & 2047;
                    const float* cr = cosp + (size_t)s * 32;
                    const float* sr = sinp + (size_t)s * 32;
                    size_t base = ((size_t)(b * Hn + hh) * S_SZ + s) * 64;
#pragma unroll
                    for (int nj = 0; nj < 2; nj++) {
                        int d = nj * 16 + c;          // 0..31
                        float x1 = acc[mi][no + nj][r];
                        float x2 = acc[mi][no + nj + 2][r];
                        float cv = cr[d], sv = sr[d];
                        dst[base + d]      = (bf16)((x1 * cv - x2 * sv) * sc);
                        dst[base + d + 32] = (bf16)((x1 * sv + x2 * cv) * sc);
                    }
                }
            }
        } else {
            // ---- V path: transposed store (b, kv, d, s)
            const int kvh = (hcol >> 6) - 40;
            const int b   = mBase >> 11;
            const int s0  = mBase & 2047;
#pragma unroll
            for (int nj = 0; nj < 4; nj++) {
                int d = nj * 16 + c;
                size_t base = ((size_t)(b * KV_SZ + kvh) * 64 + d) * (size_t)S_SZ;
#pragma unroll
                for (int mi = 0; mi < 4; mi++) {
                    int s = s0 + mi * 16 + quad * 4;
#pragma unroll
                    for (int r = 0; r < 4; r++)
                        Vtb[base + s + r] = (bf16)acc[mi][no + nj][r];
                }
            }
        }
    }
}

// ---------------------------------------------------------------- O-proj GEMM (fp32 out)
__global__ __launch_bounds__(128, 2)
void gemm_out(const bf16* __restrict__ A, const bf16* __restrict__ Bw,
              float* __restrict__ Co, int N, int K)
{
    __shared__ __align__(16) bf16 As[128 * 64];
    __shared__ __align__(16) bf16 Bs[128 * 64];

    GEMM_CORE2(A, Bw, K)

#pragma unroll
    for (int mi = 0; mi < 4; mi++)
#pragma unroll
        for (int ni = 0; ni < 8; ni++) {
            int col = colBase + ni * 16 + c;
#pragma unroll
            for (int r = 0; r < 4; r++) {
                int row = mBase + mi * 16 + quad * 4 + r;
                Co[(size_t)row * N + col] = acc[mi][ni][r];
            }
        }
}

// ---------------------------------------------------------------- flash attention
// S^T = K*Q^T so P lands q-major in LDS. P rows rotated by 8*(c&7) columns
// (mod 64): b64 writes hit all 32 banks (4 words/bank = floor, was 2x-conflicted
// on even banks only); b128 reads stay at their floor. launch_bounds(256,3)
// for 3 blocks/CU.
#define LDF 72   // 144 B row stride

__global__ __launch_bounds__(256, 3)
void flash_attn(const bf16* __restrict__ Q, const bf16* __restrict__ Kc,
                const bf16* __restrict__ Vt, bf16* __restrict__ Aout)
{
    __shared__ __align__(16) bf16 Ks[64 * LDF];
    __shared__ __align__(16) bf16 Vs[64 * LDF];
    __shared__ __align__(16) bf16 Ps[4 * 16 * LDF];

    const int tid  = threadIdx.x;
    const int lane = tid & 63;
    const int wave = tid >> 6;
    const int c = lane & 15, quad = lane >> 4;
    const int qloc = wave * 16 + c;      // q index within 64-row tile
    const int rot  = (c & 7) * 8;        // per-row P column rotation

    const int i  = blockIdx.x;           // 0..15
    const int tA = 31 - i, tB = i;       // paired q-tiles (uniform 33 passes)
    const int q0A = tA << 6, q0B = tB << 6;

    const int bh = blockIdx.y;           // b*H + h
    const int b  = bh >> 5;
    const int h  = bh & 31;
    const int kv = h >> 2;

    const bf16* Qp = Q  + (size_t)bh * (S_SZ * 64);
    const bf16* Kp = Kc + (size_t)(b * KV_SZ + kv) * (S_SZ * 64);
    const bf16* Vp = Vt + (size_t)(b * KV_SZ + kv) * (64 * S_SZ);

    // Q fragments (B-operand layout): n = lane&15, k = quad*8 (+32)
    bf16x8 aqA[2], aqB[2];
    {
        const bf16* qa = Qp + (size_t)(q0A + qloc) * 64 + quad * 8;
        aqA[0] = *(const bf16x8*)qa;  aqA[1] = *(const bf16x8*)(qa + 32);
        const bf16* qb = Qp + (size_t)(q0B + qloc) * 64 + quad * 8;
        aqB[0] = *(const bf16x8*)qb;  aqB[1] = *(const bf16x8*)(qb + 32);
    }

    f32x4 oA[4] = {}, oB[4] = {};
    f32x4 lA = {}, lB = {};

    bf16x8 ones;
#pragma unroll
    for (int j = 0; j < 8; j++) ones[j] = (bf16)1.0f;

    // staging: 256 threads cover 64x64 tile, 2 rows-of-16B each
    const int srow = tid >> 3;           // 0..31
    const int soff = (tid & 7) * 8;      // elem offset
    const bf16* Kg0 = Kp + (size_t)srow * 64 + soff;
    const bf16* Kg1 = Kp + (size_t)(srow + 32) * 64 + soff;
    const bf16* Vg0 = Vp + (size_t)srow * S_SZ + soff;
    const bf16* Vg1 = Vp + (size_t)(srow + 32) * S_SZ + soff;

    uint4 pk0 = *(const uint4*)Kg0, pk1 = *(const uint4*)Kg1;
    uint4 pv0 = *(const uint4*)Vg0, pv1 = *(const uint4*)Vg1;

    bf16* Pw = Ps + wave * 16 * LDF;     // shared between A and B phases

    for (int kt = 0; kt <= tA; kt++) {
        *(uint4*)(Ks + srow * LDF + soff)        = pk0;
        *(uint4*)(Ks + (srow + 32) * LDF + soff) = pk1;
        *(uint4*)(Vs + srow * LDF + soff)        = pv0;
        *(uint4*)(Vs + (srow + 32) * LDF + soff) = pv1;
        __syncthreads();
        if (kt < tA) {   // prefetch next tile while computing this one
            pk0 = *(const uint4*)(Kg0 + (size_t)(kt + 1) * 4096);
            pk1 = *(const uint4*)(Kg1 + (size_t)(kt + 1) * 4096);
            pv0 = *(const uint4*)(Vg0 + (kt + 1) * 64);
            pv1 = *(const uint4*)(Vg1 + (kt + 1) * 64);
        }

        // hoisted K/V fragments, shared by both q-tiles
        bf16x8 ak[2][4], av[2][4];
#pragma unroll
        for (int ks = 0; ks < 2; ks++)
#pragma unroll
            for (int ni = 0; ni < 4; ni++) {
                ak[ks][ni] = *(const bf16x8*)(Ks + (ni * 16 + c) * LDF + ks * 32 + quad * 8);
                av[ks][ni] = *(const bf16x8*)(Vs + (ni * 16 + c) * LDF + ks * 32 + quad * 8);
            }

        const bool diagA = (kt == tA);
        const bool doB   = (kt <= tB);
        const bool diagB = (kt == tB);

        // ---------------- tile A
        {
            f32x4 sc[4] = {};
#pragma unroll
            for (int ks = 0; ks < 2; ks++)
#pragma unroll
                for (int ni = 0; ni < 4; ni++)
                    sc[ni] = __builtin_amdgcn_mfma_f32_16x16x32_bf16(ak[ks][ni], aqA[ks], sc[ni], 0, 0, 0);
#pragma unroll
            for (int ni = 0; ni < 4; ni++) {
                bf16x4 pk;
#pragma unroll
                for (int r = 0; r < 4; r++) {
                    float p = exp2f(sc[ni][r]);
                    if (diagA && (ni * 16 + quad * 4 + r) > qloc) p = 0.f;
                    pk[r] = (bf16)p;
                }
                *(bf16x4*)(Pw + c * LDF + ((ni * 16 + quad * 4 + rot) & 63)) = pk;
            }
#pragma unroll
            for (int ks = 0; ks < 2; ks++) {
                bf16x8 bp = *(const bf16x8*)(Pw + c * LDF + ((ks * 32 + quad * 8 + rot) & 63));
                lA = __builtin_amdgcn_mfma_f32_16x16x32_bf16(ones, bp, lA, 0, 0, 0);
#pragma unroll
                for (int ni = 0; ni < 4; ni++)
                    oA[ni] = __builtin_amdgcn_mfma_f32_16x16x32_bf16(av[ks][ni], bp, oA[ni], 0, 0, 0);
            }
        }
        // ---------------- tile B
        if (doB) {
            f32x4 sc[4] = {};
#pragma unroll
            for (int ks = 0; ks < 2; ks++)
#pragma unroll
                for (int ni = 0; ni < 4; ni++)
                    sc[ni] = __builtin_amdgcn_mfma_f32_16x16x32_bf16(ak[ks][ni], aqB[ks], sc[ni], 0, 0, 0);
#pragma unroll
            for (int ni = 0; ni < 4; ni++) {
                bf16x4 pk;
#pragma unroll
                for (int r = 0; r < 4; r++) {
                    float p = exp2f(sc[ni][r]);
                    if (diagB && (ni * 16 + quad * 4 + r) > qloc) p = 0.f;
                    pk[r] = (bf16)p;
                }
                *(bf16x4*)(Pw + c * LDF + ((ni * 16 + quad * 4 + rot) & 63)) = pk;
            }
#pragma unroll
            for (int ks = 0; ks < 2; ks++) {
                bf16x8 bp = *(const bf16x8*)(Pw + c * LDF + ((ks * 32 + quad * 8 + rot) & 63));
                lB = __builtin_amdgcn_mfma_f32_16x16x32_bf16(ones, bp, lB, 0, 0, 0);
#pragma unroll
                for (int ni = 0; ni < 4; ni++)
                    oB[ni] = __builtin_amdgcn_mfma_f32_16x16x32_bf16(av[ks][ni], bp, oB[ni], 0, 0, 0);
            }
        }
        __syncthreads();
    }

    // epilogue: o[ni][r] = O[q=c][d=ni*16+quad*4+r]; packed 8B stores
    {
        float ila = 1.f / lA[0];
        float ilb = 1.f / lB[0];
        bf16* pa = Aout + ((size_t)(b * S_SZ + q0A + qloc)) * D_SZ + h * 64;
        bf16* pb = Aout + ((size_t)(b * S_SZ + q0B + qloc)) * D_SZ + h * 64;
#pragma unroll
        for (int ni = 0; ni < 4; ni++) {
            bf16x4 wa, wb;
#pragma unroll
            for (int r = 0; r < 4; r++) {
                wa[r] = (bf16)(oA[ni][r] * ila);
                wb[r] = (bf16)(oB[ni][r] * ilb);
            }
            *(bf16x4*)(pa + ni * 16 + quad * 4) = wa;
            *(bf16x4*)(pb + ni * 16 + quad * 4) = wb;
        }
    }
}

// ---------------------------------------------------------------- launcher
extern "C" void kernel_launch(void* const* d_in, const int* in_sizes, int n_in,
                              void* d_out, int out_size, void* d_ws, size_t ws_size,
                              hipStream_t stream) {
    const float* x    = (const float*)d_in[0];
    const float* cosp = (const float*)d_in[1];
    const float* sinp = (const float*)d_in[2];
    const float* Wq   = (const float*)d_in[3];
    const float* Wk   = (const float*)d_in[4];
    const float* Wv   = (const float*)d_in[5];
    const float* Wo   = (const float*)d_in[6];
    float* out = (float*)d_out;

    const int M = M_SZ;            // 4096
    const int D = D_SZ;            // 2048
    const int NKV = KV_SZ * HD_SZ; // 512

    // workspace layout (bf16 elems)
    bf16* xb   = (bf16*)d_ws;                    // M*D
    bf16* Wf   = xb  + (size_t)M * D;            // NQKV*D
    bf16* Qb   = Wf  + (size_t)NQKV * D;         // M*D (b,h,s,64)
    bf16* Kb   = Qb  + (size_t)M * D;            // (b,kv,s,64)
    bf16* Vtb  = Kb  + (size_t)B_SZ * KV_SZ * S_SZ * 64; // (b,kv,64,s)
    bf16* wob  = Vtb + (size_t)B_SZ * KV_SZ * 64 * S_SZ; // D*D
    bf16* attn = xb;    // alias: x dead after QKV GEMM

    const int nx = M * D / 4, n1 = D * D / 4, n2 = NKV * D / 4;

    // fused conversions (x + packed QKV weights + Wo)
    cvt_all<<<(nx + 2 * n1 + 2 * n2 + 255) / 256, 256, 0, stream>>>(
        x, Wq, Wk, Wv, Wo, xb, Wf, wob, nx, n1, n2);

    const float qscale = 0.125f * 1.44269504089f;   // 1/sqrt(hd) * log2(e)

    // fused QKV projection (+RoPE, +V transpose)
    gemm_qkv<<<dim3(NQKV / 128, M / 128), 128, 0, stream>>>(xb, Wf, Qb, Kb, Vtb, cosp, sinp, qscale);

    // flash attention -> attn (b,s,2048) bf16
    flash_attn<<<dim3(16, B_SZ * H_SZ), 256, 0, stream>>>(Qb, Kb, Vtb, attn);

    // out = attn Wo^T (fp32)
    gemm_out<<<dim3(D / 128, M / 128), 128, 0, stream>>>(attn, wob, out, D, D);
}

// Round 9
// 289.080 us; speedup vs baseline: 1.0248x; 1.0248x over previous
//
#include <hip/hip_runtime.h>
#include <hip/hip_bf16.h>

typedef __bf16 bf16;
typedef __attribute__((ext_vector_type(8))) __bf16 bf16x8;
typedef __attribute__((ext_vector_type(4))) __bf16 bf16x4;
typedef __attribute__((ext_vector_type(4))) float f32x4;

// ---------------------------------------------------------------- constants
#define B_SZ 2
#define S_SZ 2048
#define D_SZ 2048
#define H_SZ 32
#define KV_SZ 8
#define HD_SZ 64
#define M_SZ (B_SZ * S_SZ)   // 4096
#define NQKV 3072            // 2048 Q + 512 K + 512 V packed weight rows

// async global->LDS, 16B per lane; LDS dest = wave-uniform base + lane*16
#define GLDS(g, s) __builtin_amdgcn_global_load_lds( \
    (const __attribute__((address_space(1))) void*)(g), \
    (__attribute__((address_space(3))) void*)(s), 16, 0, 0)

// ---------------------------------------------------------------- fused conversions
// single dispatch: x -> xb, [Wq;Wk;Wv] -> Wf, Wo -> wob (all bf16)
__global__ void cvt_all(const float* __restrict__ x, const float* __restrict__ Wq,
                        const float* __restrict__ Wk, const float* __restrict__ Wv,
                        const float* __restrict__ Wo,
                        bf16* __restrict__ xb, bf16* __restrict__ Wf, bf16* __restrict__ wob,
                        int nx, int n1, int n2) {
    int i = blockIdx.x * blockDim.x + threadIdx.x;
    const float* src; bf16* dst; int off;
    if (i < nx)                 { src = x;  dst = xb; off = i; }
    else {
        int j = i - nx;
        if (j < n1)             { src = Wq; dst = Wf; off = j; }
        else if (j < n1 + n2)   { src = Wk; dst = Wf + (size_t)4 * n1; off = j - n1; }
        else if (j < n1 + 2*n2) { src = Wv; dst = Wf + (size_t)4 * (n1 + n2); off = j - n1 - n2; }
        else if (j < 2*n1+2*n2) { src = Wo; dst = wob; off = j - n1 - 2 * n2; }
        else return;
    }
    float4 v = ((const float4*)src)[off];
    bf16x4 o;
    o.x = (bf16)v.x; o.y = (bf16)v.y; o.z = (bf16)v.z; o.w = (bf16)v.w;
    ((bf16x4*)dst)[off] = o;
}

// ---------------------------------------------------------------- GEMM core v2
// 128-thread block (2 waves). Wave w computes rows [w*64, w*64+64) x all 128 cols
// (acc 4x8). XOR-swizzled contiguous LDS tiles [128][64] (glds-compatible):
// 16B chunk q of row r lives at position q ^ (r&7). Staging lane l fetches
// global chunk (l&7)^(l>>3) -> swizzle is free, frag b128 reads conflict-free.
#define GEMM_CORE2(A_, B_, Kdim)                                                 \
    const int tid  = threadIdx.x;                                                \
    const int w    = tid >> 6;                                                   \
    const int lane = tid & 63;                                                   \
    const int c = lane & 15, quad = lane >> 4;                                   \
    const int g8 = lane >> 3;                                                    \
    const int chs = ((lane & 7) ^ g8) * 8;                                       \
    const int rowBase = blockIdx.y * 128;                                        \
    const int colBase = blockIdx.x * 128;                                        \
    const bf16* Ag = A_ + (size_t)(rowBase + w * 64 + g8) * Kdim + chs;          \
    const bf16* Bg = B_ + (size_t)(colBase + w * 64 + g8) * Kdim + chs;          \
    bf16* sAw = As + (w * 64) * 64;                                              \
    bf16* sBw = Bs + (w * 64) * 64;                                              \
    f32x4 acc[4][8] = {};                                                        \
    for (int k0 = 0; k0 < Kdim; k0 += 64) {                                      \
        _Pragma("unroll")                                                        \
        for (int j = 0; j < 8; j++) {                                            \
            GLDS(Ag + (size_t)(j * 8) * Kdim + k0, sAw + j * 512);               \
            GLDS(Bg + (size_t)(j * 8) * Kdim + k0, sBw + j * 512);               \
        }                                                                        \
        __syncthreads();                                                         \
        _Pragma("unroll")                                                        \
        for (int ks = 0; ks < 2; ks++) {                                         \
            bf16x8 af[4], bfr[8];                                                \
            _Pragma("unroll")                                                    \
            for (int mi = 0; mi < 4; mi++)                                       \
                af[mi] = *(const bf16x8*)(As + (w * 64 + mi * 16 + c) * 64       \
                                          + (((ks << 2) + quad) ^ (c & 7)) * 8); \
            _Pragma("unroll")                                                    \
            for (int ni = 0; ni < 8; ni++)                                       \
                bfr[ni] = *(const bf16x8*)(Bs + (ni * 16 + c) * 64               \
                                          + (((ks << 2) + quad) ^ (c & 7)) * 8); \
            _Pragma("unroll")                                                    \
            for (int mi = 0; mi < 4; mi++)                                       \
                _Pragma("unroll")                                                \
                for (int ni = 0; ni < 8; ni++)                                   \
                    acc[mi][ni] = __builtin_amdgcn_mfma_f32_16x16x32_bf16(       \
                        af[mi], bfr[ni], acc[mi][ni], 0, 0, 0);                  \
        }                                                                        \
        __syncthreads();                                                         \
    }                                                                            \
    const int mBase = rowBase + w * 64;

// ---------------------------------------------------------------- fused QKV GEMM
__global__ __launch_bounds__(128, 2)
void gemm_qkv(const bf16* __restrict__ A, const bf16* __restrict__ Bw,
              bf16* __restrict__ Qb, bf16* __restrict__ Kb, bf16* __restrict__ Vtb,
              const float* __restrict__ cosp, const float* __restrict__ sinp,
              float qscale)
{
    __shared__ __align__(16) bf16 As[128 * 64];
    __shared__ __align__(16) bf16 Bs[128 * 64];

    GEMM_CORE2(A, Bw, D_SZ)

    // wave's 128 cols = two 64-wide heads; Q/K/V boundaries are 128-aligned
#pragma unroll
    for (int half = 0; half < 2; half++) {
        const int hcol = colBase + half * 64;
        const int no   = half * 4;
        if (hcol < 2560) {
            // ---- RoPE path (Q or K)
            bf16* dst; int hh, Hn; float sc;
            if (hcol < 2048) { dst = Qb; hh = hcol >> 6;        Hn = H_SZ;  sc = qscale; }
            else             { dst = Kb; hh = (hcol >> 6) - 32; Hn = KV_SZ; sc = 1.0f;  }
#pragma unroll
            for (int mi = 0; mi < 4; mi++) {
#pragma unroll
                for (int r = 0; r < 4; r++) {
                    int row = mBase + mi * 16 + quad * 4 + r;
                    int b = row >> 11;           // S = 2048
                    int s = row & 2047;
                    const float* cr = cosp + (size_t)s * 32;
                    const float* sr = sinp + (size_t)s * 32;
                    size_t base = ((size_t)(b * Hn + hh) * S_SZ + s) * 64;
#pragma unroll
                    for (int nj = 0; nj < 2; nj++) {
                        int d = nj * 16 + c;          // 0..31
                        float x1 = acc[mi][no + nj][r];
                        float x2 = acc[mi][no + nj + 2][r];
                        float cv = cr[d], sv = sr[d];
                        dst[base + d]      = (bf16)((x1 * cv - x2 * sv) * sc);
                        dst[base + d + 32] = (bf16)((x1 * sv + x2 * cv) * sc);
                    }
                }
            }
        } else {
            // ---- V path: transposed store (b, kv, d, s)
            const int kvh = (hcol >> 6) - 40;
            const int b   = mBase >> 11;
            const int s0  = mBase & 2047;
#pragma unroll
            for (int nj = 0; nj < 4; nj++) {
                int d = nj * 16 + c;
                size_t base = ((size_t)(b * KV_SZ + kvh) * 64 + d) * (size_t)S_SZ;
#pragma unroll
                for (int mi = 0; mi < 4; mi++) {
                    int s = s0 + mi * 16 + quad * 4;
#pragma unroll
                    for (int r = 0; r < 4; r++)
                        Vtb[base + s + r] = (bf16)acc[mi][no + nj][r];
                }
            }
        }
    }
}

// ---------------------------------------------------------------- O-proj GEMM (fp32 out)
__global__ __launch_bounds__(128, 2)
void gemm_out(const bf16* __restrict__ A, const bf16* __restrict__ Bw,
              float* __restrict__ Co, int N, int K)
{
    __shared__ __align__(16) bf16 As[128 * 64];
    __shared__ __align__(16) bf16 Bs[128 * 64];

    GEMM_CORE2(A, Bw, K)

#pragma unroll
    for (int mi = 0; mi < 4; mi++)
#pragma unroll
        for (int ni = 0; ni < 8; ni++) {
            int col = colBase + ni * 16 + c;
#pragma unroll
            for (int r = 0; r < 4; r++) {
                int row = mBase + mi * 16 + quad * 4 + r;
                Co[(size_t)row * N + col] = acc[mi][ni][r];
            }
        }
}

// ---------------------------------------------------------------- flash attention
// S^T = K*Q^T so P lands q-major in LDS (packed b64 writes, b128 B-operand reads).
// K/V tiles: contiguous [64][64] with GEMM-proven XOR chunk swizzle (chunk q of
// row r at q^(r&7)) -> staging stores and frag reads conflict-free.
// P: stride 72, SEPARATE regions per q-tile (A/B) so the compiler can overlap
// A's PV phase with B's QK phase (no LDS aliasing).
#define PST 72   // P row stride (elems)

__global__ __launch_bounds__(256, 3)
void flash_attn(const bf16* __restrict__ Q, const bf16* __restrict__ Kc,
                const bf16* __restrict__ Vt, bf16* __restrict__ Aout)
{
    __shared__ __align__(16) bf16 Ks[64 * 64];
    __shared__ __align__(16) bf16 Vs[64 * 64];
    __shared__ __align__(16) bf16 Ps[2 * 4 * 16 * PST];

    const int tid  = threadIdx.x;
    const int lane = tid & 63;
    const int wave = tid >> 6;
    const int c = lane & 15, quad = lane >> 4;
    const int qloc = wave * 16 + c;      // q index within 64-row tile

    const int i  = blockIdx.x;           // 0..15
    const int tA = 31 - i, tB = i;       // paired q-tiles (uniform 33 passes)
    const int q0A = tA << 6, q0B = tB << 6;

    const int bh = blockIdx.y;           // b*H + h
    const int b  = bh >> 5;
    const int h  = bh & 31;
    const int kv = h >> 2;

    const bf16* Qp = Q  + (size_t)bh * (S_SZ * 64);
    const bf16* Kp = Kc + (size_t)(b * KV_SZ + kv) * (S_SZ * 64);
    const bf16* Vp = Vt + (size_t)(b * KV_SZ + kv) * (64 * S_SZ);

    // Q fragments (B-operand layout): n = lane&15, k = quad*8 (+32)
    bf16x8 aqA[2], aqB[2];
    {
        const bf16* qa = Qp + (size_t)(q0A + qloc) * 64 + quad * 8;
        aqA[0] = *(const bf16x8*)qa;  aqA[1] = *(const bf16x8*)(qa + 32);
        const bf16* qb = Qp + (size_t)(q0B + qloc) * 64 + quad * 8;
        aqB[0] = *(const bf16x8*)qb;  aqB[1] = *(const bf16x8*)(qb + 32);
    }

    f32x4 oA[4] = {}, oB[4] = {};
    f32x4 lA = {}, lB = {};

    bf16x8 ones;
#pragma unroll
    for (int j = 0; j < 8; j++) ones[j] = (bf16)1.0f;

    // staging: 256 threads cover 64x64 tile, 2 rows-of-16B each; XOR swizzle
    const int srow = tid >> 3;                 // 0..31
    const int ch   = tid & 7;                  // global 16B chunk index
    const int sws  = (ch ^ (srow & 7)) * 8;    // swizzled LDS chunk offset (elems)
    const bf16* Kg0 = Kp + (size_t)srow * 64 + ch * 8;
    const bf16* Kg1 = Kp + (size_t)(srow + 32) * 64 + ch * 8;
    const bf16* Vg0 = Vp + (size_t)srow * S_SZ + ch * 8;
    const bf16* Vg1 = Vp + (size_t)(srow + 32) * S_SZ + ch * 8;

    uint4 pk0 = *(const uint4*)Kg0, pk1 = *(const uint4*)Kg1;
    uint4 pv0 = *(const uint4*)Vg0, pv1 = *(const uint4*)Vg1;

    bf16* PwA = Ps + wave * 16 * PST;
    bf16* PwB = Ps + (4 + wave) * 16 * PST;

    for (int kt = 0; kt <= tA; kt++) {
        *(uint4*)(Ks + srow * 64 + sws)        = pk0;
        *(uint4*)(Ks + (srow + 32) * 64 + sws) = pk1;   // (srow+32)&7 == srow&7
        *(uint4*)(Vs + srow * 64 + sws)        = pv0;
        *(uint4*)(Vs + (srow + 32) * 64 + sws) = pv1;
        __syncthreads();
        if (kt < tA) {   // prefetch next tile while computing this one
            pk0 = *(const uint4*)(Kg0 + (size_t)(kt + 1) * 4096);
            pk1 = *(const uint4*)(Kg1 + (size_t)(kt + 1) * 4096);
            pv0 = *(const uint4*)(Vg0 + (kt + 1) * 64);
            pv1 = *(const uint4*)(Vg1 + (kt + 1) * 64);
        }

        // hoisted K/V fragments (swizzled chunk), shared by both q-tiles
        bf16x8 ak[2][4], av[2][4];
#pragma unroll
        for (int ks = 0; ks < 2; ks++)
#pragma unroll
            for (int ni = 0; ni < 4; ni++) {
                const int co = (((ks << 2) + quad) ^ (c & 7)) * 8;
                ak[ks][ni] = *(const bf16x8*)(Ks + (ni * 16 + c) * 64 + co);
                av[ks][ni] = *(const bf16x8*)(Vs + (ni * 16 + c) * 64 + co);
            }

        const bool diagA = (kt == tA);
        const bool doB   = (kt <= tB);
        const bool diagB = (kt == tB);

        // ---------------- tile A
        {
            f32x4 sc[4] = {};
#pragma unroll
            for (int ks = 0; ks < 2; ks++)
#pragma unroll
                for (int ni = 0; ni < 4; ni++)
                    sc[ni] = __builtin_amdgcn_mfma_f32_16x16x32_bf16(ak[ks][ni], aqA[ks], sc[ni], 0, 0, 0);
#pragma unroll
            for (int ni = 0; ni < 4; ni++) {
                bf16x4 pk;
#pragma unroll
                for (int r = 0; r < 4; r++) {
                    float p = exp2f(sc[ni][r]);
                    if (diagA && (ni * 16 + quad * 4 + r) > qloc) p = 0.f;
                    pk[r] = (bf16)p;
                }
                *(bf16x4*)(PwA + c * PST + ni * 16 + quad * 4) = pk;
            }
#pragma unroll
            for (int ks = 0; ks < 2; ks++) {
                bf16x8 bp = *(const bf16x8*)(PwA + c * PST + ks * 32 + quad * 8);
                lA = __builtin_amdgcn_mfma_f32_16x16x32_bf16(ones, bp, lA, 0, 0, 0);
#pragma unroll
                for (int ni = 0; ni < 4; ni++)
                    oA[ni] = __builtin_amdgcn_mfma_f32_16x16x32_bf16(av[ks][ni], bp, oA[ni], 0, 0, 0);
            }
        }
        // ---------------- tile B
        if (doB) {
            f32x4 sc[4] = {};
#pragma unroll
            for (int ks = 0; ks < 2; ks++)
#pragma unroll
                for (int ni = 0; ni < 4; ni++)
                    sc[ni] = __builtin_amdgcn_mfma_f32_16x16x32_bf16(ak[ks][ni], aqB[ks], sc[ni], 0, 0, 0);
#pragma unroll
            for (int ni = 0; ni < 4; ni++) {
                bf16x4 pk;
#pragma unroll
                for (int r = 0; r < 4; r++) {
                    float p = exp2f(sc[ni][r]);
                    if (diagB && (ni * 16 + quad * 4 + r) > qloc) p = 0.f;
                    pk[r] = (bf16)p;
                }
                *(bf16x4*)(PwB + c * PST + ni * 16 + quad * 4) = pk;
            }
#pragma unroll
            for (int ks = 0; ks < 2; ks++) {
                bf16x8 bp = *(const bf16x8*)(PwB + c * PST + ks * 32 + quad * 8);
                lB = __builtin_amdgcn_mfma_f32_16x16x32_bf16(ones, bp, lB, 0, 0, 0);
#pragma unroll
                for (int ni = 0; ni < 4; ni++)
                    oB[ni] = __builtin_amdgcn_mfma_f32_16x16x32_bf16(av[ks][ni], bp, oB[ni], 0, 0, 0);
            }
        }
        __syncthreads();
    }

    // epilogue: o[ni][r] = O[q=c][d=ni*16+quad*4+r]; packed 8B stores
    {
        float ila = 1.f / lA[0];
        float ilb = 1.f / lB[0];
        bf16* pa = Aout + ((size_t)(b * S_SZ + q0A + qloc)) * D_SZ + h * 64;
        bf16* pb = Aout + ((size_t)(b * S_SZ + q0B + qloc)) * D_SZ + h * 64;
#pragma unroll
        for (int ni = 0; ni < 4; ni++) {
            bf16x4 wa, wb;
#pragma unroll
            for (int r = 0; r < 4; r++) {
                wa[r] = (bf16)(oA[ni][r] * ila);
                wb[r] = (bf16)(oB[ni][r] * ilb);
            }
            *(bf16x4*)(pa + ni * 16 + quad * 4) = wa;
            *(bf16x4*)(pb + ni * 16 + quad * 4) = wb;
        }
    }
}

// ---------------------------------------------------------------- launcher
extern "C" void kernel_launch(void* const* d_in, const int* in_sizes, int n_in,
                              void* d_out, int out_size, void* d_ws, size_t ws_size,
                              hipStream_t stream) {
    const float* x    = (const float*)d_in[0];
    const float* cosp = (const float*)d_in[1];
    const float* sinp = (const float*)d_in[2];
    const float* Wq   = (const float*)d_in[3];
    const float* Wk   = (const float*)d_in[4];
    const float* Wv   = (const float*)d_in[5];
    const float* Wo   = (const float*)d_in[6];
    float* out = (float*)d_out;

    const int M = M_SZ;            // 4096
    const int D = D_SZ;            // 2048
    const int NKV = KV_SZ * HD_SZ; // 512

    // workspace layout (bf16 elems)
    bf16* xb   = (bf16*)d_ws;                    // M*D
    bf16* Wf   = xb  + (size_t)M * D;            // NQKV*D
    bf16* Qb   = Wf  + (size_t)NQKV * D;         // M*D (b,h,s,64)
    bf16* Kb   = Qb  + (size_t)M * D;            // (b,kv,s,64)
    bf16* Vtb  = Kb  + (size_t)B_SZ * KV_SZ * S_SZ * 64; // (b,kv,64,s)
    bf16* wob  = Vtb + (size_t)B_SZ * KV_SZ * 64 * S_SZ; // D*D
    bf16* attn = xb;    // alias: x dead after QKV GEMM

    const int nx = M * D / 4, n1 = D * D / 4, n2 = NKV * D / 4;

    // fused conversions (x + packed QKV weights + Wo)
    cvt_all<<<(nx + 2 * n1 + 2 * n2 + 255) / 256, 256, 0, stream>>>(
        x, Wq, Wk, Wv, Wo, xb, Wf, wob, nx, n1, n2);

    const float qscale = 0.125f * 1.44269504089f;   // 1/sqrt(hd) * log2(e)

    // fused QKV projection (+RoPE, +V transpose)
    gemm_qkv<<<dim3(NQKV / 128, M / 128), 128, 0, stream>>>(xb, Wf, Qb, Kb, Vtb, cosp, sinp, qscale);

    // flash attention -> attn (b,s,2048) bf16
    flash_attn<<<dim3(16, B_SZ * H_SZ), 256, 0, stream>>>(Qb, Kb, Vtb, attn);

    // out = attn Wo^T (fp32)
    gemm_out<<<dim3(D / 128, M / 128), 128, 0, stream>>>(attn, wob, out, D, D);
}